// Round 6
// baseline (6076.202 us; speedup 1.0000x reference)
//
#include <hip/hip_runtime.h>
#include <math.h>

#define TT 8
#define NN 50000
#define HH 128
#define EE 800000

#define M_SCALE 0
#define M_UR    1
#define M_CAND  2
#define M_OUT   3

typedef __attribute__((ext_vector_type(8))) short short8;
typedef __attribute__((ext_vector_type(4))) short s16x4;
typedef __attribute__((ext_vector_type(4))) float f32x4;

__device__ __forceinline__ float sigmoidf_(float x){ return 1.0f/(1.0f+__expf(-x)); }

__device__ __forceinline__ short f2bf(float f){
  unsigned u = __float_as_uint(f);
  u += 0x7fff + ((u>>16)&1);
  return (short)(u>>16);
}
__device__ __forceinline__ float bf2f(short h){
  return __uint_as_float(((unsigned)(unsigned short)h)<<16);
}
__device__ __forceinline__ void split2(float f, short& h, short& l){
  h = f2bf(f); l = f2bf(f - bf2f(h));
}

// ---------------- CSR build ----------------

__global__ void count_kernel(const int* __restrict__ dst, int* __restrict__ counts){
  int e = blockIdx.x*256 + threadIdx.x;
  if (e < EE) atomicAdd(&counts[dst[e]], 1);
}

__global__ void scan_kernel(const int* __restrict__ counts, int* __restrict__ offs,
                            float* __restrict__ dinv){
  __shared__ int part[1024];
  const int t = threadIdx.x;
  const int per = (NN + 1023)/1024;
  int beg = t*per; int end = beg+per;
  if (end > NN) end = NN;
  if (beg > NN) beg = NN;
  int s = 0;
  for (int i=beg;i<end;i++) s += counts[i];
  part[t] = s; __syncthreads();
  for (int d=1; d<1024; d<<=1){
    int v = (t>=d) ? part[t-d] : 0;
    __syncthreads();
    part[t] += v;
    __syncthreads();
  }
  int run = part[t] - s;
  for (int i=beg;i<end;i++){
    offs[i] = run;
    int c = counts[i];
    run += c;
    dinv[i] = rsqrtf((float)c + 1.0f);
  }
  if (t==1023) offs[NN] = run;
}

__global__ void fill_kernel(const int* __restrict__ src, const int* __restrict__ dst,
                            const int* __restrict__ offs, int* __restrict__ cursor,
                            int* __restrict__ csr){
  int e = blockIdx.x*256 + threadIdx.x;
  if (e < EE){
    int d = dst[e];
    int p = atomicAdd(&cursor[d], 1);
    csr[offs[d]+p] = src[e];
  }
}

// ---------------- weight pre-split ----------------
// W[K][128] f32 -> WT_hi/WT_lo[c][K] bf16 (transposed)
__global__ void split_kernel(const float* __restrict__ W, short* __restrict__ WTh,
                             short* __restrict__ WTl, int K){
  int idx = blockIdx.x*256 + threadIdx.x;
  if (idx >= K*128) return;
  int c = idx & 127, k = idx >> 7;
  short h,l; split2(W[k*128 + c], h, l);
  WTh[(size_t)c*K + k] = h;
  WTl[(size_t)c*K + k] = l;
}
// [Wa | Wb] (each [256][128]) -> WT[c in 0..255][k in 0..255]
__global__ void split2_kernel(const float* __restrict__ Wa, const float* __restrict__ Wb,
                              short* __restrict__ WTh, short* __restrict__ WTl){
  int idx = blockIdx.x*256 + threadIdx.x;
  if (idx >= 256*256) return;
  int c = idx & 255, k = idx >> 8;
  const float* W = (c<128)? Wa : Wb;
  short h,l; split2(W[k*128 + (c&127)], h, l);
  WTh[(size_t)c*256 + k] = h;
  WTl[(size_t)c*256 + k] = l;
}

// ---------------- GCN aggregation (bf16 hi/lo planes) ----------------
template<int RELU>
__global__ __launch_bounds__(256) void agg_kernel(
    const short* __restrict__ Yh, const short* __restrict__ Yl,
    const int* __restrict__ csr, const int* __restrict__ offs,
    const float* __restrict__ dinv, const float* __restrict__ bias,
    short* __restrict__ Oh, short* __restrict__ Ol)
{
  const int node = blockIdx.x*8 + (threadIdx.x>>5);
  if (node >= NN) return;
  const int lane = threadIdx.x & 31;
  const s16x4* Yh4 = (const s16x4*)Yh;
  const s16x4* Yl4 = (const s16x4*)Yl;
  s16x4 sh = Yh4[(size_t)node*32 + lane];
  s16x4 sl = Yl4[(size_t)node*32 + lane];
  float acc0 = bf2f(sh[0])+bf2f(sl[0]);
  float acc1 = bf2f(sh[1])+bf2f(sl[1]);
  float acc2 = bf2f(sh[2])+bf2f(sl[2]);
  float acc3 = bf2f(sh[3])+bf2f(sl[3]);
  const int b = offs[node], e = offs[node+1];
  for (int j=b;j<e;j++){
    int s = csr[j];
    s16x4 vh = Yh4[(size_t)s*32 + lane];
    s16x4 vl = Yl4[(size_t)s*32 + lane];
    acc0 += bf2f(vh[0])+bf2f(vl[0]);
    acc1 += bf2f(vh[1])+bf2f(vl[1]);
    acc2 += bf2f(vh[2])+bf2f(vl[2]);
    acc3 += bf2f(vh[3])+bf2f(vl[3]);
  }
  const float d = dinv[node];
  const float4 bb = *(const float4*)(bias + lane*4);
  float o0 = acc0*d + bb.x;
  float o1 = acc1*d + bb.y;
  float o2 = acc2*d + bb.z;
  float o3 = acc3*d + bb.w;
  if (RELU){ o0=fmaxf(o0,0.f); o1=fmaxf(o1,0.f); o2=fmaxf(o2,0.f); o3=fmaxf(o3,0.f); }
  s16x4 oh, ol; short th, tl;
  split2(o0,th,tl); oh[0]=th; ol[0]=tl;
  split2(o1,th,tl); oh[1]=th; ol[1]=tl;
  split2(o2,th,tl); oh[2]=th; ol[2]=tl;
  split2(o3,th,tl); oh[3]=th; ol[3]=tl;
  ((s16x4*)Oh)[(size_t)node*32 + lane] = oh;
  ((s16x4*)Ol)[(size_t)node*32 + lane] = ol;
}

// ---------------- MFMA GEMM (split-bf16, 3-product) ----------------
// A = [A1] (K=128) or [A1 ; A2] (K=256), operands are bf16 hi/lo planes
// (A1 may be f32 when A1F32). Block tile 128x128, 4 waves, XOR-swizzled LDS.
// M_SCALE: O = (A@W)*dinv[row]            -> planes Oh/Ol
// M_UR   : y=blockIdx.y; v=sigmoid(+b);  y0: O=u -> Oh/Ol; y1: O=r*Q -> O2h/O2l
// M_CAND : u=P, hp=Q; O=(1-u)*hp+u*tanh(+b) -> Oh/Ol (in-place h update)
// M_OUT  : outf = A@W + b                  (f32)
template<int MODE, int K, bool A1F32>
__global__ __launch_bounds__(256,2) void mm_mfma(
    const float* __restrict__ A1f,
    const short* __restrict__ A1h, const short* __restrict__ A1l,
    const short* __restrict__ A2h, const short* __restrict__ A2l,
    const short* __restrict__ WTh, const short* __restrict__ WTl,
    const float* __restrict__ b0, const float* __restrict__ b1,
    const float* __restrict__ dinv,
    const short* __restrict__ Ph, const short* __restrict__ Pl,
    const short* __restrict__ Qh, const short* __restrict__ Ql,
    float* __restrict__ outf,
    short* __restrict__ Oh, short* __restrict__ Ol,
    short* __restrict__ O2h, short* __restrict__ O2l)
{
  __shared__ __align__(16) short Ah[128*64];
  __shared__ __align__(16) short Al[128*64];
  __shared__ __align__(16) short Bh[128*64];
  __shared__ __align__(16) short Bl[128*64];

  const int tid  = threadIdx.x;
  const int lane = tid & 63;
  const int w    = tid >> 6;
  const int bm0  = blockIdx.x * 128;
  const int row_w = (w>>1)*64, col_w = (w&1)*64;
  const int l15 = lane & 15, l4 = lane >> 4;

  f32x4 acc[4][4];
  #pragma unroll
  for (int mt=0;mt<4;mt++)
    #pragma unroll
    for (int nt=0;nt<4;nt++) acc[mt][nt] = (f32x4)(0.0f);

  const int srow  = tid >> 1;
  const int shalf = (tid & 1) * 32;
  const int grow  = bm0 + srow;
  const unsigned skey = (unsigned)(srow & 7) << 4;

  for (int kc = 0; kc < K/64; ++kc){
    const bool fromA2 = (K==256) && (kc >= 2);
    const int koff = (fromA2 ? (kc-2)*64 : kc*64) + shalf;
    // ---- stage A ----
    short8 vh[4], vl[4];
    if (grow < NN){
      if (A1F32 && !fromA2){
        const float* ap = A1f + (size_t)grow*HH + koff;
        #pragma unroll
        for (int g=0; g<4; g++){
          #pragma unroll
          for (int e=0;e<8;e++){
            short h,l; split2(ap[g*8+e], h, l);
            vh[g][e]=h; vl[g][e]=l;
          }
        }
      } else {
        const short* sh = (fromA2 ? A2h : A1h) + (size_t)grow*HH + koff;
        const short* sl = (fromA2 ? A2l : A1l) + (size_t)grow*HH + koff;
        #pragma unroll
        for (int g=0; g<4; g++){
          vh[g] = *(const short8*)(sh + g*8);
          vl[g] = *(const short8*)(sl + g*8);
        }
      }
    } else {
      #pragma unroll
      for (int g=0; g<4; g++){ vh[g] = (short8)0; vl[g] = (short8)0; }
    }
    #pragma unroll
    for (int g=0; g<4; g++){
      unsigned byte = ((unsigned)(shalf*2 + g*16)) ^ skey;
      int idx = srow*64 + (int)(byte>>1);
      *(short8*)&Ah[idx] = vh[g];
      *(short8*)&Al[idx] = vl[g];
    }
    // ---- stage B ----
    {
      const int bcol = (MODE==M_UR) ? (int)(blockIdx.y*128 + srow) : srow;
      const short* sh = WTh + (size_t)bcol*K + kc*64 + shalf;
      const short* sl = WTl + (size_t)bcol*K + kc*64 + shalf;
      #pragma unroll
      for (int g=0; g<4; g++){
        short8 wh = *(const short8*)(sh + g*8);
        short8 wl = *(const short8*)(sl + g*8);
        unsigned byte = ((unsigned)(shalf*2 + g*16)) ^ skey;
        int idx = srow*64 + (int)(byte>>1);
        *(short8*)&Bh[idx] = wh;
        *(short8*)&Bl[idx] = wl;
      }
    }
    __syncthreads();
    // ---- compute ----
    #pragma unroll
    for (int kk=0; kk<2; kk++){
      short8 ahf[4], alf[4], bhf[4], blf[4];
      #pragma unroll
      for (int mt=0; mt<4; mt++){
        int r = row_w + mt*16 + l15;
        unsigned byte = ((unsigned)(kk*64 + l4*16)) ^ ((unsigned)(r&7)<<4);
        int idx = r*64 + (int)(byte>>1);
        ahf[mt] = *(const short8*)&Ah[idx];
        alf[mt] = *(const short8*)&Al[idx];
      }
      #pragma unroll
      for (int nt=0; nt<4; nt++){
        int c = col_w + nt*16 + l15;
        unsigned byte = ((unsigned)(kk*64 + l4*16)) ^ ((unsigned)(c&7)<<4);
        int idx = c*64 + (int)(byte>>1);
        bhf[nt] = *(const short8*)&Bh[idx];
        blf[nt] = *(const short8*)&Bl[idx];
      }
      #pragma unroll
      for (int mt=0; mt<4; mt++)
        #pragma unroll
        for (int nt=0; nt<4; nt++){
          acc[mt][nt] = __builtin_amdgcn_mfma_f32_16x16x32_bf16(ahf[mt], bhf[nt], acc[mt][nt], 0,0,0);
          acc[mt][nt] = __builtin_amdgcn_mfma_f32_16x16x32_bf16(ahf[mt], blf[nt], acc[mt][nt], 0,0,0);
          acc[mt][nt] = __builtin_amdgcn_mfma_f32_16x16x32_bf16(alf[mt], bhf[nt], acc[mt][nt], 0,0,0);
        }
    }
    __syncthreads();
  }

  // ---- epilogue ----
  const int y = (MODE==M_UR) ? (int)blockIdx.y : 0;
  float bs[4] = {0.f,0.f,0.f,0.f};
  if constexpr (MODE != M_SCALE){
    const float* bb = (MODE==M_UR && y==1) ? b1 : b0;
    #pragma unroll
    for (int nt=0;nt<4;nt++) bs[nt] = bb[col_w + nt*16 + l15];
  }
  #pragma unroll
  for (int mt=0; mt<4; mt++){
    #pragma unroll
    for (int r=0; r<4; r++){
      int row = bm0 + row_w + mt*16 + l4*4 + r;
      if (row < NN){
        float dv = 0.f;
        if constexpr (MODE==M_SCALE) dv = dinv[row];
        #pragma unroll
        for (int nt=0; nt<4; nt++){
          int col = col_w + nt*16 + l15;
          size_t ix = (size_t)row*HH + col;
          float v = acc[mt][nt][r];
          if constexpr (MODE==M_SCALE){
            v *= dv;
            short h,l; split2(v,h,l);
            Oh[ix]=h; Ol[ix]=l;
          } else if constexpr (MODE==M_UR){
            v = sigmoidf_(v + bs[nt]);
            if (y==1){
              float hp = bf2f(Qh[ix]) + bf2f(Ql[ix]);
              v *= hp;
              short h,l; split2(v,h,l);
              O2h[ix]=h; O2l[ix]=l;
            } else {
              short h,l; split2(v,h,l);
              Oh[ix]=h; Ol[ix]=l;
            }
          } else if constexpr (MODE==M_CAND){
            float u  = bf2f(Ph[ix]) + bf2f(Pl[ix]);
            float hp = bf2f(Qh[ix]) + bf2f(Ql[ix]);
            v = (1.f-u)*hp + u*tanhf(v + bs[nt]);
            short h,l; split2(v,h,l);
            Oh[ix]=h; Ol[ix]=l;
          } else {
            outf[ix] = v + bs[nt];
          }
        }
      }
    }
  }
}

// ---------------- driver ----------------

extern "C" void kernel_launch(void* const* d_in, const int* in_sizes, int n_in,
                              void* d_out, int out_size, void* d_ws, size_t ws_size,
                              hipStream_t stream)
{
  const float* x_seq = (const float*)d_in[0];
  const int*   eidx  = (const int*)  d_in[1];
  const float* W_in0=(const float*)d_in[2];
  const float* b_in0=(const float*)d_in[3];
  const float* W_h0 =(const float*)d_in[4];
  const float* b_h0 =(const float*)d_in[5];
  const float* Wu0  =(const float*)d_in[6];
  const float* bu0  =(const float*)d_in[7];
  const float* Wr0  =(const float*)d_in[8];
  const float* br0  =(const float*)d_in[9];
  const float* Wc0  =(const float*)d_in[10];
  const float* bc0  =(const float*)d_in[11];
  const float* W_in1=(const float*)d_in[12];
  const float* b_in1=(const float*)d_in[13];
  const float* W_h1 =(const float*)d_in[14];
  const float* b_h1 =(const float*)d_in[15];
  const float* Wu1  =(const float*)d_in[16];
  const float* bu1  =(const float*)d_in[17];
  const float* Wr1  =(const float*)d_in[18];
  const float* br1  =(const float*)d_in[19];
  const float* Wc1  =(const float*)d_in[20];
  const float* bc1  =(const float*)d_in[21];
  const float* W_out=(const float*)d_in[22];
  const float* b_out=(const float*)d_in[23];
  float* out = (float*)d_out;

  char* p = (char*)d_ws;
  auto take = [&](size_t bytes)->void*{
    void* r = (void*)p;
    p += ((bytes + 255) & ~((size_t)255));
    return r;
  };
  const size_t pmat = (size_t)NN*HH*sizeof(short);   // one bf16 plane
  short* h0h=(short*)take(pmat); short* h0l=(short*)take(pmat);
  short* h1h=(short*)take(pmat); short* h1l=(short*)take(pmat);
  short* T1h=(short*)take(pmat); short* T1l=(short*)take(pmat);  // also U
  short* T2h=(short*)take(pmat); short* T2l=(short*)take(pmat);
  short* RHh=(short*)take(pmat); short* RHl=(short*)take(pmat);
  int*   counts=(int*)take((size_t)NN*4);
  int*   cursor=(int*)take((size_t)NN*4);
  int*   offs  =(int*)take((size_t)(NN+1)*4);
  int*   csr   =(int*)take((size_t)EE*4);
  float* dinv  =(float*)take((size_t)NN*4);

  // weights: per layer in / h / ur(combined) / c ; plus out
  short *WIh[2], *WIl[2], *WHh[2], *WHl[2], *WUh[2], *WUl[2], *WCh[2], *WCl[2];
  for (int i=0;i<2;i++){
    WIh[i]=(short*)take(128*128*2); WIl[i]=(short*)take(128*128*2);
    WHh[i]=(short*)take(128*128*2); WHl[i]=(short*)take(128*128*2);
    WUh[i]=(short*)take(256*256*2); WUl[i]=(short*)take(256*256*2);
    WCh[i]=(short*)take(128*256*2); WCl[i]=(short*)take(128*256*2);
  }
  short* WOh=(short*)take(128*128*2); short* WOl=(short*)take(128*128*2);

  hipMemsetAsync(h0h, 0, pmat, stream); hipMemsetAsync(h0l, 0, pmat, stream);
  hipMemsetAsync(h1h, 0, pmat, stream); hipMemsetAsync(h1l, 0, pmat, stream);

  split_kernel<<<64,256,0,stream>>>(W_in0, WIh[0], WIl[0], 128);
  split_kernel<<<64,256,0,stream>>>(W_h0,  WHh[0], WHl[0], 128);
  split2_kernel<<<256,256,0,stream>>>(Wu0, Wr0, WUh[0], WUl[0]);
  split_kernel<<<128,256,0,stream>>>(Wc0,  WCh[0], WCl[0], 256);
  split_kernel<<<64,256,0,stream>>>(W_in1, WIh[1], WIl[1], 128);
  split_kernel<<<64,256,0,stream>>>(W_h1,  WHh[1], WHl[1], 128);
  split2_kernel<<<256,256,0,stream>>>(Wu1, Wr1, WUh[1], WUl[1]);
  split_kernel<<<128,256,0,stream>>>(Wc1,  WCh[1], WCl[1], 256);
  split_kernel<<<64,256,0,stream>>>(W_out, WOh, WOl, 128);

  dim3 mmG((NN+127)/128), mmB(256);
  dim3 urG((NN+127)/128, 2);
  dim3 agG((NN+7)/8), agB(256);
  dim3 eG((EE+255)/256), eB(256);

  const float* bI[2] = {b_in0, b_in1};
  const float* bH[2] = {b_h0, b_h1};
  const float* bU[2] = {bu0, bu1};
  const float* bR[2] = {br0, br1};
  const float* bC[2] = {bc0, bc1};
  short* Sh[2] = {h0h, h1h};
  short* Sl[2] = {h0l, h1l};

  for (int t=0; t<TT; ++t){
    const int* src = eidx + (size_t)t*2*EE;
    const int* dst = src + EE;
    const float* xt = x_seq + (size_t)t*NN*HH;
    float* outt = out + (size_t)t*NN*HH;

    hipMemsetAsync(counts, 0, (size_t)NN*4, stream);
    hipMemsetAsync(cursor, 0, (size_t)NN*4, stream);
    count_kernel<<<eG,eB,0,stream>>>(dst, counts);
    scan_kernel<<<1,1024,0,stream>>>(counts, offs, dinv);
    fill_kernel<<<eG,eB,0,stream>>>(src, dst, offs, cursor, csr);

    for (int l=0; l<2; ++l){
      short* hh = Sh[l]; short* hl = Sl[l];
      // GCN1: Y = (in @ W_in)*dinv ; agg+relu
      if (l==0)
        mm_mfma<M_SCALE,128,true><<<mmG,mmB,0,stream>>>(xt, nullptr,nullptr, nullptr,nullptr,
            WIh[0],WIl[0], nullptr,nullptr, dinv, nullptr,nullptr, nullptr,nullptr,
            nullptr, T1h,T1l, nullptr,nullptr);
      else
        mm_mfma<M_SCALE,128,false><<<mmG,mmB,0,stream>>>(nullptr, h0h,h0l, nullptr,nullptr,
            WIh[1],WIl[1], nullptr,nullptr, dinv, nullptr,nullptr, nullptr,nullptr,
            nullptr, T1h,T1l, nullptr,nullptr);
      agg_kernel<1><<<agG,agB,0,stream>>>(T1h,T1l, csr, offs, dinv, bI[l], T2h,T2l);
      // GCN2
      mm_mfma<M_SCALE,128,false><<<mmG,mmB,0,stream>>>(nullptr, T2h,T2l, nullptr,nullptr,
          WHh[l],WHl[l], nullptr,nullptr, dinv, nullptr,nullptr, nullptr,nullptr,
          nullptr, T1h,T1l, nullptr,nullptr);
      agg_kernel<0><<<agG,agB,0,stream>>>(T1h,T1l, csr, offs, dinv, bH[l], T2h,T2l);
      // fused u,r gates: u -> T1 planes, r*h_prev -> RH planes
      mm_mfma<M_UR,256,false><<<urG,mmB,0,stream>>>(nullptr, T2h,T2l, hh,hl,
          WUh[l],WUl[l], bU[l], bR[l], nullptr, nullptr,nullptr, hh,hl,
          nullptr, T1h,T1l, RHh,RHl);
      // candidate + GRU update (in-place h)
      mm_mfma<M_CAND,256,false><<<mmG,mmB,0,stream>>>(nullptr, T2h,T2l, RHh,RHl,
          WCh[l],WCl[l], bC[l], nullptr, nullptr, T1h,T1l, hh,hl,
          nullptr, hh,hl, nullptr,nullptr);
    }
    // output projection (f32 out)
    mm_mfma<M_OUT,128,false><<<mmG,mmB,0,stream>>>(nullptr, h1h,h1l, nullptr,nullptr,
        WOh,WOl, b_out, nullptr, nullptr, nullptr,nullptr, nullptr,nullptr,
        outt, nullptr,nullptr, nullptr,nullptr);
  }
}